// Round 1
// baseline (846.329 us; speedup 1.0000x reference)
//
#include <hip/hip_runtime.h>
#include <math.h>

#define Nn 1024
#define Cn 192
#define KEPT 256
#define COMP 512
#define UT 128
#define KT 64
#define C4q 48   // Cn/4

// ---------------- Kernel A: w[b][c] = 1 / sum_n x[b][n][c]^2 ----------------
__global__ __launch_bounds__(192) void norm_kernel(const float* __restrict__ x,
                                                   float* __restrict__ w) {
    int b = blockIdx.x;
    int c = threadIdx.x;                       // 0..191, coalesced over c
    const float* xb = x + (size_t)b * Nn * Cn + c;
    float s[8] = {0.f,0.f,0.f,0.f,0.f,0.f,0.f,0.f};
    for (int n = 0; n < Nn; n += 8) {
        #pragma unroll
        for (int q = 0; q < 8; ++q) {
            float v = xb[(size_t)(n + q) * Cn];
            s[q] += v * v;
        }
    }
    float t0 = (s[0] + s[1]) + (s[2] + s[3]);
    float t1 = (s[4] + s[5]) + (s[6] + s[7]);
    w[b * Cn + c] = 1.0f / (t0 + t1);
}

// ------------- Kernel B: dst_idx[b][u] = argmax_k sim (k=0 excluded) -------------
// block = 256 threads, computes a 128u x 256k sim tile for one b, k-tiled by 64.
// LDS: su = unimp rows * w (128x192 f32 as f4, XOR-swizzled), sk = imp rows (64x192).
__global__ __launch_bounds__(256) void sim_argmax_kernel(const float* __restrict__ x,
                                                         const float* __restrict__ w,
                                                         int* __restrict__ dst_idx) {
    __shared__ float4 su[UT * C4q];   // 98304 B
    __shared__ float4 sk[KT * C4q];   // 49152 B
    __shared__ float  wl[Cn];         //   768 B

    const int b  = blockIdx.y;
    const int u0 = blockIdx.x * UT;
    const int t  = threadIdx.x;

    const float* xb = x + (size_t)b * Nn * Cn;

    if (t < Cn) wl[t] = w[b * Cn + t];
    __syncthreads();

    // stage su = x[b, KEPT+u0+r, :] * w[b,:]
    #pragma unroll
    for (int i = 0; i < UT * C4q / 256; ++i) {   // 24 iters
        int idx = t + 256 * i;
        int r = idx / C4q, c4 = idx % C4q;
        const float* src = xb + (size_t)(KEPT + u0 + r) * Cn + c4 * 4;
        float4 v;
        v.x = src[0] * wl[c4 * 4 + 0];
        v.y = src[1] * wl[c4 * 4 + 1];
        v.z = src[2] * wl[c4 * 4 + 2];
        v.w = src[3] * wl[c4 * 4 + 3];
        su[r * C4q + (c4 ^ ((r >> 3) & 7))] = v;   // XOR swizzle on f4 index
    }

    const int ti = t >> 4;   // 0..15 -> u rows ti*8 .. ti*8+7
    const int tk = t & 15;   // 0..15 -> k cols tk*4 .. tk*4+3 within k-tile
    const int xa = ti & 7;

    float best_v[8];
    int   best_i[8];
    #pragma unroll
    for (int i = 0; i < 8; ++i) { best_v[i] = -INFINITY; best_i[i] = 0; }

    for (int kt = 0; kt < KEPT / KT; ++kt) {
        __syncthreads();   // covers su stores (kt=0) / prior reads of sk (kt>0)
        #pragma unroll
        for (int i = 0; i < KT * C4q / 256; ++i) {  // 12 iters
            int idx = t + 256 * i;
            int r = idx / C4q, c4 = idx % C4q;
            float4 v = *reinterpret_cast<const float4*>(
                xb + (size_t)(kt * KT + r) * Cn + c4 * 4);
            sk[r * C4q + (c4 ^ ((r >> 3) & 7))] = v;
        }
        __syncthreads();

        float acc[8][4];
        #pragma unroll
        for (int i = 0; i < 8; ++i)
            #pragma unroll
            for (int j = 0; j < 4; ++j) acc[i][j] = 0.f;

        for (int c4 = 0; c4 < C4q; ++c4) {
            float4 a[8];
            #pragma unroll
            for (int i = 0; i < 8; ++i)
                a[i] = su[(ti * 8 + i) * C4q + (c4 ^ xa)];
            float4 bb[4];
            #pragma unroll
            for (int j = 0; j < 4; ++j) {
                int r = tk * 4 + j;
                bb[j] = sk[r * C4q + (c4 ^ ((r >> 3) & 7))];
            }
            #pragma unroll
            for (int i = 0; i < 8; ++i)
                #pragma unroll
                for (int j = 0; j < 4; ++j) {
                    acc[i][j] += a[i].x * bb[j].x;
                    acc[i][j] += a[i].y * bb[j].y;
                    acc[i][j] += a[i].z * bb[j].z;
                    acc[i][j] += a[i].w * bb[j].w;
                }
        }

        // running argmax (k ascending within thread -> strict > keeps lowest k)
        #pragma unroll
        for (int i = 0; i < 8; ++i)
            #pragma unroll
            for (int j = 0; j < 4; ++j) {
                int k = kt * KT + tk * 4 + j;
                if (k != 0 && acc[i][j] > best_v[i]) {
                    best_v[i] = acc[i][j]; best_i[i] = k;
                }
            }
    }

    // argmax-reduce across the 16 consecutive lanes sharing ti (tie -> lower k)
    #pragma unroll
    for (int i = 0; i < 8; ++i) {
        #pragma unroll
        for (int off = 1; off < 16; off <<= 1) {
            float vv = __shfl_xor(best_v[i], off);
            int   ii = __shfl_xor(best_i[i], off);
            if (vv > best_v[i] || (vv == best_v[i] && ii < best_i[i])) {
                best_v[i] = vv; best_i[i] = ii;
            }
        }
    }
    if (tk == 0) {
        #pragma unroll
        for (int i = 0; i < 8; ++i)
            dst_idx[b * COMP + u0 + ti * 8 + i] = best_i[i];
    }
}

// ------------- Kernel C: scatter-add + mean -> out -------------
// grid (512 b, 3 c-chunks of 64), block 256.
__global__ __launch_bounds__(256) void merge_kernel(const float* __restrict__ x,
                                                    const int* __restrict__ dst_idx,
                                                    float* __restrict__ out) {
    __shared__ float sums[KEPT][64];   // 65536 B
    __shared__ float cnt[KEPT];
    __shared__ int   sidx[COMP];

    int b = blockIdx.x;
    int cbase = blockIdx.y * 64;
    int t = threadIdx.x;

    for (int i = t; i < KEPT * 64; i += 256) ((float*)sums)[i] = 0.f;
    if (t < KEPT) cnt[t] = 0.f;
    sidx[t]       = dst_idx[b * COMP + t];
    sidx[t + 256] = dst_idx[b * COMP + t + 256];
    __syncthreads();

    atomicAdd(&cnt[sidx[t]], 1.0f);
    atomicAdd(&cnt[sidx[t + 256]], 1.0f);

    const float* xb = x + (size_t)b * Nn * Cn;
    int c  = t & 63;
    int ug = t >> 6;                       // 0..3
    for (int step = 0; step < COMP / 4; ++step) {
        int u = step * 4 + ug;
        float v = xb[(size_t)(KEPT + u) * Cn + cbase + c];
        atomicAdd(&sums[sidx[u]][c], v);
    }
    __syncthreads();

    float* outb = out + (size_t)b * KEPT * Cn;
    for (int i = t; i < KEPT * 64; i += 256) {
        int k = i >> 6, cc = i & 63;
        float d = xb[(size_t)k * Cn + cbase + cc];
        outb[(size_t)k * Cn + cbase + cc] = (d + sums[k][cc]) / (cnt[k] + 1.0f);
    }
}

extern "C" void kernel_launch(void* const* d_in, const int* in_sizes, int n_in,
                              void* d_out, int out_size, void* d_ws, size_t ws_size,
                              hipStream_t stream) {
    const float* x = (const float*)d_in[0];
    float* out = (float*)d_out;

    float* w       = (float*)d_ws;                                     // 512*192 f32
    int*   dst_idx = (int*)((char*)d_ws + (size_t)512 * Cn * 4);       // 512*512 i32

    norm_kernel<<<dim3(512), dim3(192), 0, stream>>>(x, w);
    sim_argmax_kernel<<<dim3(COMP / UT, 512), dim3(256), 0, stream>>>(x, w, dst_idx);
    merge_kernel<<<dim3(512, 3), dim3(256), 0, stream>>>(x, dst_idx, out);
}